// Round 17
// baseline (305.430 us; speedup 1.0000x reference)
//
#include <hip/hip_runtime.h>
#include <hip/hip_bf16.h>

#define N_TOK 131072
#define NCHUNK 1024
#define NBINS 8192
#define HSTR 8448

typedef __bf16 bf16_t;
typedef bf16_t bf16x4 __attribute__((ext_vector_type(4)));
typedef bf16_t bf16x8 __attribute__((ext_vector_type(8)));
typedef float f32x4 __attribute__((ext_vector_type(4)));
typedef float f32x16 __attribute__((ext_vector_type(16)));

__device__ __forceinline__ unsigned pkbf(float a, float b) {
  unsigned r;
  asm("v_cvt_pk_bf16_f32 %0, %1, %2" : "=v"(r) : "v"(a), "v"(b));
  return r;
}
__device__ __forceinline__ void pl32swap(unsigned& x, unsigned& y) {
  asm("v_permlane32_swap_b32 %0, %1" : "+v"(x), "+v"(y));
}
// lgkm-only barrier: orders LDS traffic, leaves global loads/stores in flight
// (all inter-phase deps are LDS-only; rule #18 sched_barrier included)
__device__ __forceinline__ void bar_lgkm() {
  asm volatile("s_waitcnt lgkmcnt(0)" ::: "memory");
  __builtin_amdgcn_s_barrier();
  __builtin_amdgcn_sched_barrier(0);
}
// fragment-region byte address inside the reused hL region:
// frow = head*128 + tok (0..1023), 32B per frag row, 272B super-rows.
__device__ __forceinline__ int fra(int frow, int colb) {
  return (frow >> 3) * 272 + (frow & 7) * 32 + colb;
}

// window key decomposition (matches reference _window_keys)
__device__ __forceinline__ void win_keys(int b, int z, int y, int x, int r,
                                         int& bwi, int& cell) {
  int wx = x / 12, wy = y / 12, wz = z >> 5;
  int cx = x % 12, cy = y % 12, cz = z & 31;
  if (r == 0) { bwi = b * 1922 + wx * 62 + wy * 2 + wz; cell = cx * 384 + cy * 32 + cz; }
  else        { bwi = b * 1922 + wy * 62 + wx * 2 + wz; cell = cy * 384 + cx * 32 + cz; }
}

// merged: weight prep + window histogram (independent work, one launch)
__global__ void k_pre(const float* __restrict__ Wqkv, const float* __restrict__ Wo,
                      const int* __restrict__ coords, bf16_t* __restrict__ Wt,
                      bf16_t* __restrict__ Wot, int* __restrict__ hist) {
  int t = blockIdx.x * 256 + threadIdx.x;
  if (t < 98304) {                    // 2 * 384 * 128, [i][n][k]
    int i = t / 49152, rem = t % 49152, n = rem / 128, k = rem % 128;
    float v = Wqkv[(i * 128 + k) * 384 + n];
    if (n < 128) v *= 0.36067376022224085f;   // fold 0.25*log2(e) into Wq
    Wt[t] = (bf16_t)v;
  } else {
    int u = t - 98304;                // 2 * 128 * 128, [i][e][d]
    int i = u / 16384, rem = u % 16384, e = rem / 128, d = rem % 128;
    Wot[u] = (bf16_t)Wo[(i * 128 + d) * 128 + e];
  }
  int4 c = ((const int4*)coords)[t];  // b,z,y,x
  int bwi, cell;
  win_keys(c.x, c.y, c.z, c.w, 0, bwi, cell);
  atomicAdd(&hist[bwi], 1);
  win_keys(c.x, c.y, c.z, c.w, 1, bwi, cell);
  atomicAdd(&hist[HSTR + bwi], 1);
}

__global__ void k_scan(const int* __restrict__ histb, int* __restrict__ startsb,
                       int* __restrict__ curb) {
  int r = blockIdx.x;
  const int* hist = histb + r * HSTR;
  int* starts = startsb + r * HSTR;
  int* cur = curb + r * HSTR;
  __shared__ int ssum[256];
  int tid = threadIdx.x;
  int base = tid * 32;
  int s = 0;
  for (int j = 0; j < 32; j++) s += hist[base + j];
  ssum[tid] = s;
  __syncthreads();
  if (tid == 0) {
    int acc = 0;
    for (int i = 0; i < 256; i++) { int v = ssum[i]; ssum[i] = acc; acc += v; }
  }
  __syncthreads();
  int run = ssum[tid];
  for (int j = 0; j < 32; j++) {
    starts[base + j] = run; cur[base + j] = run; run += hist[base + j];
  }
  if (tid == 255) starts[NBINS] = run;
}

__global__ void k_scatter(const int* __restrict__ coords, int* __restrict__ cur,
                          int* __restrict__ seg) {
  int t = blockIdx.x * 256 + threadIdx.x;
  int4 c = ((const int4*)coords)[t];
  int bwi, cell;
  win_keys(c.x, c.y, c.z, c.w, 0, bwi, cell);
  seg[atomicAdd(&cur[bwi], 1)] = (cell << 17) | t;
  win_keys(c.x, c.y, c.z, c.w, 1, bwi, cell);
  seg[N_TOK + atomicAdd(&cur[HSTR + bwi], 1)] = (cell << 17) | t;
}

// per-window stable finish: sort segment ascending by packed (cell, idx)
__global__ void k_winsort(const int* __restrict__ startsb, const int* __restrict__ segb,
                          int* __restrict__ orderb) {
  int r = blockIdx.y;
  const int* starts = startsb + r * HSTR;
  const int* seg = segb + r * N_TOK;
  int* order = orderb + r * N_TOK;
  int w = blockIdx.x;
  int s = starts[w], m = starts[w + 1] - s;
  for (int i = threadIdx.x; i < m; i += 256) {
    int v = seg[s + i], rk = 0;
    for (int j = 0; j < m; j++) rk += (seg[s + j] < v);
    order[s + rk] = v & 0x1FFFF;
  }
}

// ======================== fused per-chunk block (v5) =========================
// 512 blocks x 512 thr; each block does chunks bid and bid+512. All barriers
// lgkm-only. Chunk-2 gather prefetched into regs before chunk-1 phase C
// (phase C has zero vmem ops -> loads ride under it). Phase C in 2 kt-groups
// (sc[2] live, 32 regs) to stay under the 128-VGPR / 4-waves-per-SIMD ceiling.
#define VSW(d) ((((d) >> 3) & 7) << 4)
__global__ __launch_bounds__(512, 4) void k_fused(
    const bf16_t* __restrict__ Wt, const bf16_t* __restrict__ Wot,
    const int* __restrict__ order, const float* __restrict__ ln_g,
    const float* __restrict__ ln_b, const float* __restrict__ xin,
    float* __restrict__ xout) {
  __shared__ bf16_t hL[128 * 136];
  __shared__ bf16_t vT[128 * 136];
  char* hLb = (char*)hL;
  int tid = threadIdx.x, wv = tid >> 6, lane = tid & 63;
  int l16 = lane & 15, gk = 8 * (lane >> 4), r4 = (lane >> 4) * 4;
  int l31 = lane & 31, hi = lane >> 5;
  int row4 = tid >> 2, g4 = tid & 3;

  // prologue: gather chunk bid
  float4 pv[8];
  int tokp = order[blockIdx.x * 128 + row4];
  {
    const float4* src = (const float4*)(xin + (size_t)tokp * 128) + g4 * 8;
    #pragma unroll
    for (int j = 0; j < 8; j++) pv[j] = src[j];
  }

  #pragma unroll
  for (int half = 0; half < 2; half++) {
    int chunk = blockIdx.x + half * 512;

    // ---- phase 0: layernorm from prefetched regs -> hL
    {
      float s = 0.f, sq = 0.f;
      #pragma unroll
      for (int j = 0; j < 8; j++) {
        s += pv[j].x + pv[j].y + pv[j].z + pv[j].w;
        sq += pv[j].x * pv[j].x + pv[j].y * pv[j].y + pv[j].z * pv[j].z + pv[j].w * pv[j].w;
      }
      s += __shfl_xor(s, 1); sq += __shfl_xor(sq, 1);
      s += __shfl_xor(s, 2); sq += __shfl_xor(sq, 2);
      float mean = s * 0.0078125f;
      float var = sq * 0.0078125f - mean * mean;
      float rstd = rsqrtf(var + 1e-5f);
      #pragma unroll
      for (int j = 0; j < 8; j++) {
        float4 gv = ((const float4*)ln_g)[g4 * 8 + j];
        float4 bv = ((const float4*)ln_b)[g4 * 8 + j];
        bf16x4 o;
        o[0] = (bf16_t)((pv[j].x - mean) * rstd * gv.x + bv.x);
        o[1] = (bf16_t)((pv[j].y - mean) * rstd * gv.y + bv.y);
        o[2] = (bf16_t)((pv[j].z - mean) * rstd * gv.z + bv.z);
        o[3] = (bf16_t)((pv[j].w - mean) * rstd * gv.w + bv.w);
        *(bf16x4*)(&hL[row4 * 136 + g4 * 32 + j * 4]) = o;
      }
    }
    bar_lgkm();

    // ---- phase B: V projection -> swizzled vT[d][tok] (LDS)
    {
      int wr = wv >> 2, wc = wv & 3;
      f32x4 acc[4][2] = {};
      #pragma unroll
      for (int ks = 0; ks < 4; ks++) {
        int k0 = ks * 32 + gk;
        bf16x8 a[4], b[2];
        #pragma unroll
        for (int mi = 0; mi < 4; mi++)
          a[mi] = *(const bf16x8*)(&hL[(wr * 64 + mi * 16 + l16) * 136 + k0]);
        #pragma unroll
        for (int ni = 0; ni < 2; ni++)
          b[ni] = *(const bf16x8*)(Wt + (size_t)(256 + wc * 32 + ni * 16 + l16) * 128 + k0);
        #pragma unroll
        for (int mi = 0; mi < 4; mi++)
          #pragma unroll
          for (int ni = 0; ni < 2; ni++)
            acc[mi][ni] = __builtin_amdgcn_mfma_f32_16x16x32_bf16(a[mi], b[ni], acc[mi][ni], 0, 0, 0);
      }
      #pragma unroll
      for (int mi = 0; mi < 4; mi++)
        #pragma unroll
        for (int ni = 0; ni < 2; ni++) {
          int d = wc * 32 + ni * 16 + l16;
          int tok0 = wr * 64 + mi * 16 + r4;
          bf16x4 o;
          #pragma unroll
          for (int e = 0; e < 4; e++) o[e] = (bf16_t)acc[mi][ni][e];
          *(bf16x4*)((char*)vT + ((d * 272 + tok0 * 2) ^ VSW(d))) = o;
        }
    }

    // ---- phase A: QK projection (swapped: C[n][tok]); pieces in regs
    uint2 px[4][4];
    int wrA = wv >> 1, wcA = wv & 1;
    {
      f32x4 acc[4][4] = {};
      #pragma unroll
      for (int ks = 0; ks < 4; ks++) {
        int k0 = ks * 32 + gk;
        bf16x8 a[4], b[4];
        #pragma unroll
        for (int mi = 0; mi < 4; mi++)
          a[mi] = *(const bf16x8*)(Wt + (size_t)(wrA * 64 + mi * 16 + l16) * 128 + k0);
        #pragma unroll
        for (int ni = 0; ni < 4; ni++)
          b[ni] = *(const bf16x8*)(&hL[(wcA * 64 + ni * 16 + l16) * 136 + k0]);
        #pragma unroll
        for (int mi = 0; mi < 4; mi++)
          #pragma unroll
          for (int ni = 0; ni < 4; ni++)
            acc[mi][ni] = __builtin_amdgcn_mfma_f32_16x16x32_bf16(a[mi], b[ni], acc[mi][ni], 0, 0, 0);
      }
      #pragma unroll
      for (int mi = 0; mi < 4; mi++)
        #pragma unroll
        for (int ni = 0; ni < 4; ni++) {
          bf16x4 o;
          #pragma unroll
          for (int e = 0; e < 4; e++) o[e] = (bf16_t)acc[mi][ni][e];
          px[mi][ni] = __builtin_bit_cast(uint2, o);
        }
    }
    bar_lgkm();   // h dead, vT ready; hL region reusable as frag buffer

    // ---- K-frag write (wv>=4) -> kf regs -> Q-frag write (wv<4)
    bool isK = (wv >= 4);
    if (isK) {
      #pragma unroll
      for (int mi = 0; mi < 4; mi++)
        #pragma unroll
        for (int ni = 0; ni < 4; ni++) {
          int n = wrA * 64 + mi * 16 + r4;
          int tok = wcA * 64 + ni * 16 + l16;
          int head = (n >> 4) & 7;
          *(uint2*)(hLb + fra(head * 128 + tok, (n & 15) * 2)) = px[mi][ni];
        }
    }
    bar_lgkm();
    bf16x8 kf[4];
    #pragma unroll
    for (int kt = 0; kt < 4; kt++)
      kf[kt] = *(const bf16x8*)(hLb + fra(wv * 128 + 32 * kt + l31, hi * 16));
    bar_lgkm();
    if (!isK) {
      #pragma unroll
      for (int mi = 0; mi < 4; mi++)
        #pragma unroll
        for (int ni = 0; ni < 4; ni++) {
          int n = wrA * 64 + mi * 16 + r4;
          int tok = wcA * 64 + ni * 16 + l16;
          int head = (n >> 4) & 7;
          *(uint2*)(hLb + fra(head * 128 + tok, (n & 15) * 2)) = px[mi][ni];
        }
    }
    bar_lgkm();

    // ---- prefetch chunk-2 gather (vmem; rides under phase C, which has
    // no vmem ops and only lgkm barriers)
    if (half == 0) {
      tokp = order[(blockIdx.x + 512) * 128 + row4];
      const float4* src = (const float4*)(xin + (size_t)tokp * 128) + g4 * 8;
      #pragma unroll
      for (int j = 0; j < 8; j++) pv[j] = src[j];
    }

    // ---- phase C: attention; wave = head; 2 kt-groups (sum/C accumulate
    // across groups -- valid for no-max softmax with deferred 1/sum)
    {
      int dvt = wv * 16 + (l31 & 15);
      #pragma unroll 1
      for (int qt = 0; qt < 4; qt++) {
        bf16x8 qf = *(const bf16x8*)(hLb + fra(wv * 128 + 32 * qt + l31, hi * 16));
        float sum = 0.f;
        f32x16 C = {};
        #pragma unroll
        for (int g = 0; g < 2; g++) {
          f32x16 sc0, sc1;
          __builtin_amdgcn_s_setprio(1);
          {
            f32x16 z0 = {}, z1 = {};
            sc0 = __builtin_amdgcn_mfma_f32_32x32x16_bf16(kf[2 * g], qf, z0, 0, 0, 0);
            sc1 = __builtin_amdgcn_mfma_f32_32x32x16_bf16(kf[2 * g + 1], qf, z1, 0, 0, 0);
          }
          __builtin_amdgcn_s_setprio(0);
          uint4 pfw[4];
          #pragma unroll
          for (int j = 0; j < 4; j++) {
            const f32x16& sct = (j < 2) ? sc0 : sc1;
            int sl = (j & 1) * 8;
            float p0 = __builtin_amdgcn_exp2f(sct[sl + 0]);
            float p1 = __builtin_amdgcn_exp2f(sct[sl + 1]);
            float p2 = __builtin_amdgcn_exp2f(sct[sl + 2]);
            float p3 = __builtin_amdgcn_exp2f(sct[sl + 3]);
            float p4 = __builtin_amdgcn_exp2f(sct[sl + 4]);
            float p5 = __builtin_amdgcn_exp2f(sct[sl + 5]);
            float p6 = __builtin_amdgcn_exp2f(sct[sl + 6]);
            float p7 = __builtin_amdgcn_exp2f(sct[sl + 7]);
            sum += ((p0 + p1) + (p2 + p3)) + ((p4 + p5) + (p6 + p7));
            unsigned X0 = pkbf(p0, p1), X1 = pkbf(p2, p3);
            unsigned Y0 = pkbf(p4, p5), Y1 = pkbf(p6, p7);
            pl32swap(X0, Y0);
            pl32swap(X1, Y1);
            pfw[j] = (uint4){X0, X1, Y0, Y1};
          }
          __builtin_amdgcn_s_setprio(1);
          #pragma unroll
          for (int j = 0; j < 4; j++) {
            int s = 4 * g + j;
            bf16x8 pf = __builtin_bit_cast(bf16x8, pfw[j]);
            bf16x8 vf = *(const bf16x8*)((const char*)vT +
                         ((dvt * 272 + (16 * s + 8 * hi) * 2) ^ VSW(dvt)));
            C = __builtin_amdgcn_mfma_f32_32x32x16_bf16(pf, vf, C, 0, 0, 0);
          }
          __builtin_amdgcn_s_setprio(0);
        }
        sum += __shfl_xor(sum, 32);
        float inv = 1.0f / sum;
        #pragma unroll
        for (int e = 0; e < 16; e++) {
          int row = (e & 3) + 8 * (e >> 2) + 4 * hi;
          float rsv = __shfl(inv, row, 32);
          if (l31 < 16)
            *(bf16_t*)(hLb + fra(wv * 128 + 32 * qt + row, l31 * 2)) =
                (bf16_t)(C[e] * rsv);
        }
      }
    }
    bar_lgkm();

    // ---- phase D: out-projection + f32 residual; ao from frag layout
    {
      int wr = wv >> 2, wc = wv & 3;
      int qr = wr * 64, qc = wc * 32;
      f32x4 acc[4][2] = {};
      #pragma unroll
      for (int ks = 0; ks < 4; ks++) {
        int k0 = ks * 32 + gk;
        bf16x8 a[4], b[2];
        #pragma unroll
        for (int mi = 0; mi < 4; mi++)
          a[mi] = *(const bf16x8*)(hLb +
                   fra((k0 >> 4) * 128 + (qr + mi * 16 + l16), (k0 & 8) * 2));
        #pragma unroll
        for (int ni = 0; ni < 2; ni++)
          b[ni] = *(const bf16x8*)(Wot + (qc + ni * 16 + l16) * 128 + k0);
        #pragma unroll
        for (int mi = 0; mi < 4; mi++)
          #pragma unroll
          for (int ni = 0; ni < 2; ni++)
            acc[mi][ni] = __builtin_amdgcn_mfma_f32_16x16x32_bf16(a[mi], b[ni], acc[mi][ni], 0, 0, 0);
      }
      #pragma unroll
      for (int mi = 0; mi < 4; mi++) {
        #pragma unroll
        for (int e = 0; e < 4; e++) {
          int row = qr + mi * 16 + r4 + e;
          int tok = order[chunk * 128 + row];
          #pragma unroll
          for (int ni = 0; ni < 2; ni++) {
            int col = qc + ni * 16 + l16;
            xout[(size_t)tok * 128 + col] = xin[(size_t)tok * 128 + col] + acc[mi][ni][e];
          }
        }
      }
    }
    if (half == 0) bar_lgkm();   // hL frag reads done before chunk-2 LN writes
  }
}

extern "C" void kernel_launch(void* const* d_in, const int* in_sizes, int n_in,
                              void* d_out, int out_size, void* d_ws, size_t ws_size,
                              hipStream_t stream) {
  const int* coords = (const int*)d_in[0];
  const float* feats = (const float*)d_in[1];
  const float* Wqkv = (const float*)d_in[2];
  const float* Wo = (const float*)d_in[3];
  const float* ln_g = (const float*)d_in[4];
  const float* ln_b = (const float*)d_in[5];
  float* out = (float*)d_out;

  char* w = (char*)d_ws;
  size_t off = 0;
  auto take = [&](size_t b) { char* p = w + off; off += (b + 255) & ~(size_t)255; return p; };
  int* hist   = (int*)take(2 * HSTR * 4);
  int* starts = (int*)take(2 * HSTR * 4);
  int* cur    = (int*)take(2 * HSTR * 4);
  int* seg    = (int*)take(2 * (size_t)N_TOK * 4);
  int* order  = (int*)take(2 * (size_t)N_TOK * 4);
  bf16_t* Wt  = (bf16_t*)take(2 * 384 * 128 * 2);
  bf16_t* Wot = (bf16_t*)take(2 * 128 * 128 * 2);

  hipMemsetAsync(hist, 0, 2 * HSTR * 4, stream);
  k_pre<<<512, 256, 0, stream>>>(Wqkv, Wo, coords, Wt, Wot, hist);
  k_scan<<<2, 256, 0, stream>>>(hist, starts, cur);
  k_scatter<<<512, 256, 0, stream>>>(coords, cur, seg);
  k_winsort<<<dim3(NBINS, 2), 256, 0, stream>>>(starts, seg, order);

  for (int r = 0; r < 2; r++) {
    const float* xin = (r == 0) ? feats : out;
    k_fused<<<512, 512, 0, stream>>>(Wt + r * 49152, Wot + r * 16384,
                                     order + r * N_TOK, ln_g + r * 128,
                                     ln_b + r * 128, xin, out);
  }
}

// Round 18
// 222.468 us; speedup vs baseline: 1.3729x; 1.3729x over previous
//
#include <hip/hip_runtime.h>
#include <hip/hip_bf16.h>

#define N_TOK 131072
#define NCHUNK 1024
#define NBINS 8192
#define HSTR 8448

typedef __bf16 bf16_t;
typedef bf16_t bf16x4 __attribute__((ext_vector_type(4)));
typedef bf16_t bf16x8 __attribute__((ext_vector_type(8)));
typedef float f32x4 __attribute__((ext_vector_type(4)));
typedef float f32x16 __attribute__((ext_vector_type(16)));

__device__ __forceinline__ unsigned pkbf(float a, float b) {
  unsigned r;
  asm("v_cvt_pk_bf16_f32 %0, %1, %2" : "=v"(r) : "v"(a), "v"(b));
  return r;
}
__device__ __forceinline__ void pl32swap(unsigned& x, unsigned& y) {
  asm("v_permlane32_swap_b32 %0, %1" : "+v"(x), "+v"(y));
}
// lgkm-only barrier: orders LDS traffic, leaves global loads/stores in flight.
// All inter-phase deps in k_fused are LDS-only (rule #18 sched_barrier incl.)
__device__ __forceinline__ void bar_lgkm() {
  asm volatile("s_waitcnt lgkmcnt(0)" ::: "memory");
  __builtin_amdgcn_s_barrier();
  __builtin_amdgcn_sched_barrier(0);
}
// fragment-region byte address inside the reused hL region:
// frow = head*128 + tok (0..1023), 32B per frag row, 272B super-rows.
__device__ __forceinline__ int fra(int frow, int colb) {
  return (frow >> 3) * 272 + (frow & 7) * 32 + colb;
}

// window key decomposition (matches reference _window_keys)
__device__ __forceinline__ void win_keys(int b, int z, int y, int x, int r,
                                         int& bwi, int& cell) {
  int wx = x / 12, wy = y / 12, wz = z >> 5;
  int cx = x % 12, cy = y % 12, cz = z & 31;
  if (r == 0) { bwi = b * 1922 + wx * 62 + wy * 2 + wz; cell = cx * 384 + cy * 32 + cz; }
  else        { bwi = b * 1922 + wy * 62 + wx * 2 + wz; cell = cy * 384 + cx * 32 + cz; }
}

// merged: weight prep + window histogram (independent work, one launch)
__global__ void k_pre(const float* __restrict__ Wqkv, const float* __restrict__ Wo,
                      const int* __restrict__ coords, bf16_t* __restrict__ Wt,
                      bf16_t* __restrict__ Wot, int* __restrict__ hist) {
  int t = blockIdx.x * 256 + threadIdx.x;
  if (t < 98304) {                    // 2 * 384 * 128, [i][n][k]
    int i = t / 49152, rem = t % 49152, n = rem / 128, k = rem % 128;
    float v = Wqkv[(i * 128 + k) * 384 + n];
    if (n < 128) v *= 0.36067376022224085f;   // fold 0.25*log2(e) into Wq
    Wt[t] = (bf16_t)v;
  } else {
    int u = t - 98304;                // 2 * 128 * 128, [i][e][d]
    int i = u / 16384, rem = u % 16384, e = rem / 128, d = rem % 128;
    Wot[u] = (bf16_t)Wo[(i * 128 + d) * 128 + e];
  }
  int4 c = ((const int4*)coords)[t];  // b,z,y,x
  int bwi, cell;
  win_keys(c.x, c.y, c.z, c.w, 0, bwi, cell);
  atomicAdd(&hist[bwi], 1);
  win_keys(c.x, c.y, c.z, c.w, 1, bwi, cell);
  atomicAdd(&hist[HSTR + bwi], 1);
}

__global__ void k_scan(const int* __restrict__ histb, int* __restrict__ startsb,
                       int* __restrict__ curb) {
  int r = blockIdx.x;
  const int* hist = histb + r * HSTR;
  int* starts = startsb + r * HSTR;
  int* cur = curb + r * HSTR;
  __shared__ int ssum[256];
  int tid = threadIdx.x;
  int base = tid * 32;
  int s = 0;
  for (int j = 0; j < 32; j++) s += hist[base + j];
  ssum[tid] = s;
  __syncthreads();
  if (tid == 0) {
    int acc = 0;
    for (int i = 0; i < 256; i++) { int v = ssum[i]; ssum[i] = acc; acc += v; }
  }
  __syncthreads();
  int run = ssum[tid];
  for (int j = 0; j < 32; j++) {
    starts[base + j] = run; cur[base + j] = run; run += hist[base + j];
  }
  if (tid == 255) starts[NBINS] = run;
}

__global__ void k_scatter(const int* __restrict__ coords, int* __restrict__ cur,
                          int* __restrict__ seg) {
  int t = blockIdx.x * 256 + threadIdx.x;
  int4 c = ((const int4*)coords)[t];
  int bwi, cell;
  win_keys(c.x, c.y, c.z, c.w, 0, bwi, cell);
  seg[atomicAdd(&cur[bwi], 1)] = (cell << 17) | t;
  win_keys(c.x, c.y, c.z, c.w, 1, bwi, cell);
  seg[N_TOK + atomicAdd(&cur[HSTR + bwi], 1)] = (cell << 17) | t;
}

// per-window stable finish: sort segment ascending by packed (cell, idx).
// 64 threads (windows hold ~16 tokens; 256 was 75% idle).
__global__ void k_winsort(const int* __restrict__ startsb, const int* __restrict__ segb,
                          int* __restrict__ orderb) {
  int r = blockIdx.y;
  const int* starts = startsb + r * HSTR;
  const int* seg = segb + r * N_TOK;
  int* order = orderb + r * N_TOK;
  int w = blockIdx.x;
  int s = starts[w], m = starts[w + 1] - s;
  for (int i = threadIdx.x; i < m; i += 64) {
    int v = seg[s + i], rk = 0;
    for (int j = 0; j < m; j++) rk += (seg[s + j] < v);
    order[s + rk] = v & 0x1FFFF;
  }
}

// ======================== fused per-chunk block (v4 + lgkm barriers) =========
// 512 thr / 8 waves. LDS: hL[128][136] + vT[128][136] = 69.6 KB -> 2 blocks/CU.
// Q/K handoff entirely in LDS (hL region reused as fragment buffer). All
// barriers lgkm-only: no vmcnt(0) drains (inter-phase deps are LDS-only).
#define VSW(d) ((((d) >> 3) & 7) << 4)
__global__ __launch_bounds__(512, 4) void k_fused(
    const bf16_t* __restrict__ Wt, const bf16_t* __restrict__ Wot,
    const int* __restrict__ order, const float* __restrict__ ln_g,
    const float* __restrict__ ln_b, const float* __restrict__ xin,
    float* __restrict__ xout) {
  int chunk = blockIdx.x;
  __shared__ bf16_t hL[128 * 136];
  __shared__ bf16_t vT[128 * 136];
  char* hLb = (char*)hL;
  int tid = threadIdx.x, wv = tid >> 6, lane = tid & 63;
  int l16 = lane & 15, gk = 8 * (lane >> 4), r4 = (lane >> 4) * 4;
  int l31 = lane & 31, hi = lane >> 5;

  // ---- phase 0: gather + layernorm -> hL (4 threads per row)
  {
    int row = tid >> 2, g = tid & 3;
    int tok = order[chunk * 128 + row];
    const float4* src = (const float4*)(xin + (size_t)tok * 128) + g * 8;
    float4 v[8];
    #pragma unroll
    for (int j = 0; j < 8; j++) v[j] = src[j];
    float s = 0.f, sq = 0.f;
    #pragma unroll
    for (int j = 0; j < 8; j++) {
      s += v[j].x + v[j].y + v[j].z + v[j].w;
      sq += v[j].x * v[j].x + v[j].y * v[j].y + v[j].z * v[j].z + v[j].w * v[j].w;
    }
    s += __shfl_xor(s, 1); sq += __shfl_xor(sq, 1);
    s += __shfl_xor(s, 2); sq += __shfl_xor(sq, 2);
    float mean = s * 0.0078125f;
    float var = sq * 0.0078125f - mean * mean;
    float rstd = rsqrtf(var + 1e-5f);
    #pragma unroll
    for (int j = 0; j < 8; j++) {
      float4 gv = ((const float4*)ln_g)[g * 8 + j];
      float4 bv = ((const float4*)ln_b)[g * 8 + j];
      bf16x4 o;
      o[0] = (bf16_t)((v[j].x - mean) * rstd * gv.x + bv.x);
      o[1] = (bf16_t)((v[j].y - mean) * rstd * gv.y + bv.y);
      o[2] = (bf16_t)((v[j].z - mean) * rstd * gv.z + bv.z);
      o[3] = (bf16_t)((v[j].w - mean) * rstd * gv.w + bv.w);
      *(bf16x4*)(&hL[row * 136 + g * 32 + j * 4]) = o;
    }
  }
  bar_lgkm();

  // ---- phase B: V projection: C[tok][d] -> swizzled vT[d][tok] (LDS)
  {
    int wr = wv >> 2, wc = wv & 3;       // 64-tok block, 32-d block
    f32x4 acc[4][2] = {};
    #pragma unroll
    for (int ks = 0; ks < 4; ks++) {
      int k0 = ks * 32 + gk;
      bf16x8 a[4], b[2];
      #pragma unroll
      for (int mi = 0; mi < 4; mi++)
        a[mi] = *(const bf16x8*)(&hL[(wr * 64 + mi * 16 + l16) * 136 + k0]);
      #pragma unroll
      for (int ni = 0; ni < 2; ni++)
        b[ni] = *(const bf16x8*)(Wt + (size_t)(256 + wc * 32 + ni * 16 + l16) * 128 + k0);
      #pragma unroll
      for (int mi = 0; mi < 4; mi++)
        #pragma unroll
        for (int ni = 0; ni < 2; ni++)
          acc[mi][ni] = __builtin_amdgcn_mfma_f32_16x16x32_bf16(a[mi], b[ni], acc[mi][ni], 0, 0, 0);
    }
    #pragma unroll
    for (int mi = 0; mi < 4; mi++)
      #pragma unroll
      for (int ni = 0; ni < 2; ni++) {
        int d = wc * 32 + ni * 16 + l16;
        int tok0 = wr * 64 + mi * 16 + r4;
        bf16x4 o;
        #pragma unroll
        for (int e = 0; e < 4; e++) o[e] = (bf16_t)acc[mi][ni][e];
        *(bf16x4*)((char*)vT + ((d * 272 + tok0 * 2) ^ VSW(d))) = o;
      }
  }

  // ---- phase A: QK projection (swapped: C[n][tok]); pieces held in regs
  uint2 px[4][4];
  int wrA = wv >> 1, wcA = wv & 1;       // 64-n block, 64-tok block
  {
    f32x4 acc[4][4] = {};
    #pragma unroll
    for (int ks = 0; ks < 4; ks++) {
      int k0 = ks * 32 + gk;
      bf16x8 a[4], b[4];
      #pragma unroll
      for (int mi = 0; mi < 4; mi++)
        a[mi] = *(const bf16x8*)(Wt + (size_t)(wrA * 64 + mi * 16 + l16) * 128 + k0);
      #pragma unroll
      for (int ni = 0; ni < 4; ni++)
        b[ni] = *(const bf16x8*)(&hL[(wcA * 64 + ni * 16 + l16) * 136 + k0]);
      #pragma unroll
      for (int mi = 0; mi < 4; mi++)
        #pragma unroll
        for (int ni = 0; ni < 4; ni++)
          acc[mi][ni] = __builtin_amdgcn_mfma_f32_16x16x32_bf16(a[mi], b[ni], acc[mi][ni], 0, 0, 0);
    }
    #pragma unroll
    for (int mi = 0; mi < 4; mi++)
      #pragma unroll
      for (int ni = 0; ni < 4; ni++) {
        bf16x4 o;
        #pragma unroll
        for (int e = 0; e < 4; e++) o[e] = (bf16_t)acc[mi][ni][e];
        px[mi][ni] = __builtin_bit_cast(uint2, o);
      }
  }
  bar_lgkm();   // all hL(h) + vT deps done; hL region now reusable

  // ---- K-frag write (waves with n>=128), then kf load, then Q-frag write
  bool isK = (wv >= 4);
  if (isK) {
    #pragma unroll
    for (int mi = 0; mi < 4; mi++)
      #pragma unroll
      for (int ni = 0; ni < 4; ni++) {
        int n = wrA * 64 + mi * 16 + r4;
        int tok = wcA * 64 + ni * 16 + l16;
        int head = (n >> 4) & 7;
        *(uint2*)(hLb + fra(head * 128 + tok, (n & 15) * 2)) = px[mi][ni];
      }
  }
  bar_lgkm();
  bf16x8 kf[4];
  #pragma unroll
  for (int kt = 0; kt < 4; kt++)
    kf[kt] = *(const bf16x8*)(hLb + fra(wv * 128 + 32 * kt + l31, hi * 16));
  bar_lgkm();
  if (!isK) {
    #pragma unroll
    for (int mi = 0; mi < 4; mi++)
      #pragma unroll
      for (int ni = 0; ni < 4; ni++) {
        int n = wrA * 64 + mi * 16 + r4;
        int tok = wcA * 64 + ni * 16 + l16;
        int head = (n >> 4) & 7;
        *(uint2*)(hLb + fra(head * 128 + tok, (n & 15) * 2)) = px[mi][ni];
      }
  }
  bar_lgkm();

  // ---- phase C: attention; wave = head; qf from LDS frag region; ao written
  // back into the consumed qf rows (per-head regions disjoint -> no races)
  {
    int dvt = wv * 16 + (l31 & 15);
    #pragma unroll 1
    for (int qt = 0; qt < 4; qt++) {
      bf16x8 qf = *(const bf16x8*)(hLb + fra(wv * 128 + 32 * qt + l31, hi * 16));
      f32x16 sc[4];
      __builtin_amdgcn_s_setprio(1);
      #pragma unroll
      for (int kt = 0; kt < 4; kt++) {
        f32x16 z = {};
        sc[kt] = __builtin_amdgcn_mfma_f32_32x32x16_bf16(kf[kt], qf, z, 0, 0, 0);
      }
      __builtin_amdgcn_s_setprio(0);
      // no-max softmax; 0.25*log2(e) pre-folded into Wq -> raw v_exp_f32.
      float sum = 0.f;
      uint4 pfw[8];
      #pragma unroll
      for (int s = 0; s < 8; s++) {
        int t = s >> 1, sl = (s & 1) * 8;
        float p0 = __builtin_amdgcn_exp2f(sc[t][sl + 0]);
        float p1 = __builtin_amdgcn_exp2f(sc[t][sl + 1]);
        float p2 = __builtin_amdgcn_exp2f(sc[t][sl + 2]);
        float p3 = __builtin_amdgcn_exp2f(sc[t][sl + 3]);
        float p4 = __builtin_amdgcn_exp2f(sc[t][sl + 4]);
        float p5 = __builtin_amdgcn_exp2f(sc[t][sl + 5]);
        float p6 = __builtin_amdgcn_exp2f(sc[t][sl + 6]);
        float p7 = __builtin_amdgcn_exp2f(sc[t][sl + 7]);
        sum += ((p0 + p1) + (p2 + p3)) + ((p4 + p5) + (p6 + p7));
        unsigned X0 = pkbf(p0, p1), X1 = pkbf(p2, p3);
        unsigned Y0 = pkbf(p4, p5), Y1 = pkbf(p6, p7);
        pl32swap(X0, Y0);
        pl32swap(X1, Y1);
        pfw[s] = (uint4){X0, X1, Y0, Y1};
      }
      sum += __shfl_xor(sum, 32);
      float inv = 1.0f / sum;
      f32x16 C = {};
      __builtin_amdgcn_s_setprio(1);
      #pragma unroll
      for (int s = 0; s < 8; s++) {
        bf16x8 pf = __builtin_bit_cast(bf16x8, pfw[s]);
        bf16x8 vf = *(const bf16x8*)((const char*)vT +
                     ((dvt * 272 + (16 * s + 8 * hi) * 2) ^ VSW(dvt)));
        C = __builtin_amdgcn_mfma_f32_32x32x16_bf16(pf, vf, C, 0, 0, 0);
      }
      __builtin_amdgcn_s_setprio(0);
      #pragma unroll
      for (int e = 0; e < 16; e++) {
        int row = (e & 3) + 8 * (e >> 2) + 4 * hi;
        float rsv = __shfl(inv, row, 32);
        if (l31 < 16)
          *(bf16_t*)(hLb + fra(wv * 128 + 32 * qt + row, l31 * 2)) =
              (bf16_t)(C[e] * rsv);
      }
    }
  }
  bar_lgkm();

  // ---- phase D: out-projection + f32 residual; ao from frag layout
  {
    int wr = wv >> 2, wc = wv & 3;
    int qr = wr * 64, qc = wc * 32;
    f32x4 acc[4][2] = {};
    #pragma unroll
    for (int ks = 0; ks < 4; ks++) {
      int k0 = ks * 32 + gk;
      bf16x8 a[4], b[2];
      #pragma unroll
      for (int mi = 0; mi < 4; mi++)
        a[mi] = *(const bf16x8*)(hLb +
                 fra((k0 >> 4) * 128 + (qr + mi * 16 + l16), (k0 & 8) * 2));
      #pragma unroll
      for (int ni = 0; ni < 2; ni++)
        b[ni] = *(const bf16x8*)(Wot + (qc + ni * 16 + l16) * 128 + k0);
      #pragma unroll
      for (int mi = 0; mi < 4; mi++)
        #pragma unroll
        for (int ni = 0; ni < 2; ni++)
          acc[mi][ni] = __builtin_amdgcn_mfma_f32_16x16x32_bf16(a[mi], b[ni], acc[mi][ni], 0, 0, 0);
    }
    #pragma unroll
    for (int mi = 0; mi < 4; mi++) {
      #pragma unroll
      for (int e = 0; e < 4; e++) {
        int row = qr + mi * 16 + r4 + e;
        int tok = order[chunk * 128 + row];
        #pragma unroll
        for (int ni = 0; ni < 2; ni++) {
          int col = qc + ni * 16 + l16;
          xout[(size_t)tok * 128 + col] = xin[(size_t)tok * 128 + col] + acc[mi][ni][e];
        }
      }
    }
  }
}

extern "C" void kernel_launch(void* const* d_in, const int* in_sizes, int n_in,
                              void* d_out, int out_size, void* d_ws, size_t ws_size,
                              hipStream_t stream) {
  const int* coords = (const int*)d_in[0];
  const float* feats = (const float*)d_in[1];
  const float* Wqkv = (const float*)d_in[2];
  const float* Wo = (const float*)d_in[3];
  const float* ln_g = (const float*)d_in[4];
  const float* ln_b = (const float*)d_in[5];
  float* out = (float*)d_out;

  char* w = (char*)d_ws;
  size_t off = 0;
  auto take = [&](size_t b) { char* p = w + off; off += (b + 255) & ~(size_t)255; return p; };
  int* hist   = (int*)take(2 * HSTR * 4);
  int* starts = (int*)take(2 * HSTR * 4);
  int* cur    = (int*)take(2 * HSTR * 4);
  int* seg    = (int*)take(2 * (size_t)N_TOK * 4);
  int* order  = (int*)take(2 * (size_t)N_TOK * 4);
  bf16_t* Wt  = (bf16_t*)take(2 * 384 * 128 * 2);
  bf16_t* Wot = (bf16_t*)take(2 * 128 * 128 * 2);

  hipMemsetAsync(hist, 0, 2 * HSTR * 4, stream);
  k_pre<<<512, 256, 0, stream>>>(Wqkv, Wo, coords, Wt, Wot, hist);
  k_scan<<<2, 256, 0, stream>>>(hist, starts, cur);
  k_scatter<<<512, 256, 0, stream>>>(coords, cur, seg);
  k_winsort<<<dim3(NBINS, 2), 64, 0, stream>>>(starts, seg, order);

  for (int r = 0; r < 2; r++) {
    const float* xin = (r == 0) ? feats : out;
    k_fused<<<NCHUNK, 512, 0, stream>>>(Wt + r * 49152, Wot + r * 16384,
                                        order + r * N_TOK, ln_g + r * 128,
                                        ln_b + r * 128, xin, out);
  }
}

// Round 19
// 221.542 us; speedup vs baseline: 1.3787x; 1.0042x over previous
//
#include <hip/hip_runtime.h>
#include <hip/hip_bf16.h>

#define N_TOK 131072
#define NCHUNK 1024
#define NBINS 8192
#define HSTR 8448

typedef __bf16 bf16_t;
typedef bf16_t bf16x4 __attribute__((ext_vector_type(4)));
typedef bf16_t bf16x8 __attribute__((ext_vector_type(8)));
typedef float f32x4 __attribute__((ext_vector_type(4)));
typedef float f32x16 __attribute__((ext_vector_type(16)));

__device__ __forceinline__ unsigned pkbf(float a, float b) {
  unsigned r;
  asm("v_cvt_pk_bf16_f32 %0, %1, %2" : "=v"(r) : "v"(a), "v"(b));
  return r;
}
__device__ __forceinline__ void pl32swap(unsigned& x, unsigned& y) {
  asm("v_permlane32_swap_b32 %0, %1" : "+v"(x), "+v"(y));
}
// lgkm-only barrier: orders LDS traffic, leaves global loads/stores in flight.
// All inter-phase deps in k_fused are LDS-only (rule #18 sched_barrier incl.)
__device__ __forceinline__ void bar_lgkm() {
  asm volatile("s_waitcnt lgkmcnt(0)" ::: "memory");
  __builtin_amdgcn_s_barrier();
  __builtin_amdgcn_sched_barrier(0);
}
// fragment-region byte address inside the reused hL region:
// frow = head*128 + tok (0..1023), 32B per frag row, 272B super-rows.
__device__ __forceinline__ int fra(int frow, int colb) {
  return (frow >> 3) * 272 + (frow & 7) * 32 + colb;
}

// window key decomposition (matches reference _window_keys)
__device__ __forceinline__ void win_keys(int b, int z, int y, int x, int r,
                                         int& bwi, int& cell) {
  int wx = x / 12, wy = y / 12, wz = z >> 5;
  int cx = x % 12, cy = y % 12, cz = z & 31;
  if (r == 0) { bwi = b * 1922 + wx * 62 + wy * 2 + wz; cell = cx * 384 + cy * 32 + cz; }
  else        { bwi = b * 1922 + wy * 62 + wx * 2 + wz; cell = cy * 384 + cx * 32 + cz; }
}

// merged: weight prep + window histogram (independent work, one launch)
__global__ void k_pre(const float* __restrict__ Wqkv, const float* __restrict__ Wo,
                      const int* __restrict__ coords, bf16_t* __restrict__ Wt,
                      bf16_t* __restrict__ Wot, int* __restrict__ hist) {
  int t = blockIdx.x * 256 + threadIdx.x;
  if (t < 98304) {                    // 2 * 384 * 128, [i][n][k]
    int i = t / 49152, rem = t % 49152, n = rem / 128, k = rem % 128;
    float v = Wqkv[(i * 128 + k) * 384 + n];
    if (n < 128) v *= 0.36067376022224085f;   // fold 0.25*log2(e) into Wq
    Wt[t] = (bf16_t)v;
  } else {
    int u = t - 98304;                // 2 * 128 * 128, [i][e][d]
    int i = u / 16384, rem = u % 16384, e = rem / 128, d = rem % 128;
    Wot[u] = (bf16_t)Wo[(i * 128 + d) * 128 + e];
  }
  int4 c = ((const int4*)coords)[t];  // b,z,y,x
  int bwi, cell;
  win_keys(c.x, c.y, c.z, c.w, 0, bwi, cell);
  atomicAdd(&hist[bwi], 1);
  win_keys(c.x, c.y, c.z, c.w, 1, bwi, cell);
  atomicAdd(&hist[HSTR + bwi], 1);
}

// block-parallel exclusive scan (Hillis-Steele over 256 partials)
__global__ void k_scan(const int* __restrict__ histb, int* __restrict__ startsb,
                       int* __restrict__ curb) {
  int r = blockIdx.x;
  const int* hist = histb + r * HSTR;
  int* starts = startsb + r * HSTR;
  int* cur = curb + r * HSTR;
  __shared__ int ssum[256];
  int tid = threadIdx.x;
  int base = tid * 32;
  int s = 0;
  for (int j = 0; j < 32; j++) s += hist[base + j];
  ssum[tid] = s;
  __syncthreads();
  int val = s;
  #pragma unroll
  for (int off = 1; off < 256; off <<= 1) {
    int t = (tid >= off) ? ssum[tid - off] : 0;
    __syncthreads();
    val += t;
    ssum[tid] = val;
    __syncthreads();
  }
  int run = val - s;   // exclusive prefix
  for (int j = 0; j < 32; j++) {
    starts[base + j] = run; cur[base + j] = run; run += hist[base + j];
  }
  if (tid == 255) starts[NBINS] = run;
}

__global__ void k_scatter(const int* __restrict__ coords, int* __restrict__ cur,
                          int* __restrict__ seg) {
  int t = blockIdx.x * 256 + threadIdx.x;
  int4 c = ((const int4*)coords)[t];
  int bwi, cell;
  win_keys(c.x, c.y, c.z, c.w, 0, bwi, cell);
  seg[atomicAdd(&cur[bwi], 1)] = (cell << 17) | t;
  win_keys(c.x, c.y, c.z, c.w, 1, bwi, cell);
  seg[N_TOK + atomicAdd(&cur[HSTR + bwi], 1)] = (cell << 17) | t;
}

// per-window stable finish: sort segment ascending by packed (cell, idx).
__global__ void k_winsort(const int* __restrict__ startsb, const int* __restrict__ segb,
                          int* __restrict__ orderb) {
  int r = blockIdx.y;
  const int* starts = startsb + r * HSTR;
  const int* seg = segb + r * N_TOK;
  int* order = orderb + r * N_TOK;
  int w = blockIdx.x;
  int s = starts[w], m = starts[w + 1] - s;
  for (int i = threadIdx.x; i < m; i += 64) {
    int v = seg[s + i], rk = 0;
    for (int j = 0; j < m; j++) rk += (seg[s + j] < v);
    order[s + rk] = v & 0x1FFFF;
  }
}

// ======================== fused per-chunk block (v4 + lgkm + split-C) ========
// 512 thr / 8 waves. LDS: hL[128][136] + vT[128][136] = 69.6 KB -> 2 blocks/CU.
// Q/K handoff entirely in LDS (hL region reused as fragment buffer). lgkm-only
// barriers. PV accumulator split C0/C1 to halve the dependent-MFMA chain.
#define VSW(d) ((((d) >> 3) & 7) << 4)
__global__ __launch_bounds__(512, 4) void k_fused(
    const bf16_t* __restrict__ Wt, const bf16_t* __restrict__ Wot,
    const int* __restrict__ order, const float* __restrict__ ln_g,
    const float* __restrict__ ln_b, const float* __restrict__ xin,
    float* __restrict__ xout) {
  int chunk = blockIdx.x;
  __shared__ bf16_t hL[128 * 136];
  __shared__ bf16_t vT[128 * 136];
  char* hLb = (char*)hL;
  int tid = threadIdx.x, wv = tid >> 6, lane = tid & 63;
  int l16 = lane & 15, gk = 8 * (lane >> 4), r4 = (lane >> 4) * 4;
  int l31 = lane & 31, hi = lane >> 5;

  // ---- phase 0: gather + layernorm -> hL (4 threads per row)
  {
    int row = tid >> 2, g = tid & 3;
    int tok = order[chunk * 128 + row];
    const float4* src = (const float4*)(xin + (size_t)tok * 128) + g * 8;
    float4 v[8];
    #pragma unroll
    for (int j = 0; j < 8; j++) v[j] = src[j];
    float s = 0.f, sq = 0.f;
    #pragma unroll
    for (int j = 0; j < 8; j++) {
      s += v[j].x + v[j].y + v[j].z + v[j].w;
      sq += v[j].x * v[j].x + v[j].y * v[j].y + v[j].z * v[j].z + v[j].w * v[j].w;
    }
    s += __shfl_xor(s, 1); sq += __shfl_xor(sq, 1);
    s += __shfl_xor(s, 2); sq += __shfl_xor(sq, 2);
    float mean = s * 0.0078125f;
    float var = sq * 0.0078125f - mean * mean;
    float rstd = rsqrtf(var + 1e-5f);
    #pragma unroll
    for (int j = 0; j < 8; j++) {
      float4 gv = ((const float4*)ln_g)[g * 8 + j];
      float4 bv = ((const float4*)ln_b)[g * 8 + j];
      bf16x4 o;
      o[0] = (bf16_t)((v[j].x - mean) * rstd * gv.x + bv.x);
      o[1] = (bf16_t)((v[j].y - mean) * rstd * gv.y + bv.y);
      o[2] = (bf16_t)((v[j].z - mean) * rstd * gv.z + bv.z);
      o[3] = (bf16_t)((v[j].w - mean) * rstd * gv.w + bv.w);
      *(bf16x4*)(&hL[row * 136 + g * 32 + j * 4]) = o;
    }
  }
  bar_lgkm();

  // ---- phase B: V projection: C[tok][d] -> swizzled vT[d][tok] (LDS)
  {
    int wr = wv >> 2, wc = wv & 3;       // 64-tok block, 32-d block
    f32x4 acc[4][2] = {};
    #pragma unroll
    for (int ks = 0; ks < 4; ks++) {
      int k0 = ks * 32 + gk;
      bf16x8 a[4], b[2];
      #pragma unroll
      for (int mi = 0; mi < 4; mi++)
        a[mi] = *(const bf16x8*)(&hL[(wr * 64 + mi * 16 + l16) * 136 + k0]);
      #pragma unroll
      for (int ni = 0; ni < 2; ni++)
        b[ni] = *(const bf16x8*)(Wt + (size_t)(256 + wc * 32 + ni * 16 + l16) * 128 + k0);
      #pragma unroll
      for (int mi = 0; mi < 4; mi++)
        #pragma unroll
        for (int ni = 0; ni < 2; ni++)
          acc[mi][ni] = __builtin_amdgcn_mfma_f32_16x16x32_bf16(a[mi], b[ni], acc[mi][ni], 0, 0, 0);
    }
    #pragma unroll
    for (int mi = 0; mi < 4; mi++)
      #pragma unroll
      for (int ni = 0; ni < 2; ni++) {
        int d = wc * 32 + ni * 16 + l16;
        int tok0 = wr * 64 + mi * 16 + r4;
        bf16x4 o;
        #pragma unroll
        for (int e = 0; e < 4; e++) o[e] = (bf16_t)acc[mi][ni][e];
        *(bf16x4*)((char*)vT + ((d * 272 + tok0 * 2) ^ VSW(d))) = o;
      }
  }

  // ---- phase A: QK projection (swapped: C[n][tok]); pieces held in regs
  uint2 px[4][4];
  int wrA = wv >> 1, wcA = wv & 1;       // 64-n block, 64-tok block
  {
    f32x4 acc[4][4] = {};
    #pragma unroll
    for (int ks = 0; ks < 4; ks++) {
      int k0 = ks * 32 + gk;
      bf16x8 a[4], b[4];
      #pragma unroll
      for (int mi = 0; mi < 4; mi++)
        a[mi] = *(const bf16x8*)(Wt + (size_t)(wrA * 64 + mi * 16 + l16) * 128 + k0);
      #pragma unroll
      for (int ni = 0; ni < 4; ni++)
        b[ni] = *(const bf16x8*)(&hL[(wcA * 64 + ni * 16 + l16) * 136 + k0]);
      #pragma unroll
      for (int mi = 0; mi < 4; mi++)
        #pragma unroll
        for (int ni = 0; ni < 4; ni++)
          acc[mi][ni] = __builtin_amdgcn_mfma_f32_16x16x32_bf16(a[mi], b[ni], acc[mi][ni], 0, 0, 0);
    }
    #pragma unroll
    for (int mi = 0; mi < 4; mi++)
      #pragma unroll
      for (int ni = 0; ni < 4; ni++) {
        bf16x4 o;
        #pragma unroll
        for (int e = 0; e < 4; e++) o[e] = (bf16_t)acc[mi][ni][e];
        px[mi][ni] = __builtin_bit_cast(uint2, o);
      }
  }
  bar_lgkm();   // all hL(h) + vT deps done; hL region now reusable

  // ---- K-frag write (waves with n>=128), then kf load, then Q-frag write
  bool isK = (wv >= 4);
  if (isK) {
    #pragma unroll
    for (int mi = 0; mi < 4; mi++)
      #pragma unroll
      for (int ni = 0; ni < 4; ni++) {
        int n = wrA * 64 + mi * 16 + r4;
        int tok = wcA * 64 + ni * 16 + l16;
        int head = (n >> 4) & 7;
        *(uint2*)(hLb + fra(head * 128 + tok, (n & 15) * 2)) = px[mi][ni];
      }
  }
  bar_lgkm();
  bf16x8 kf[4];
  #pragma unroll
  for (int kt = 0; kt < 4; kt++)
    kf[kt] = *(const bf16x8*)(hLb + fra(wv * 128 + 32 * kt + l31, hi * 16));
  bar_lgkm();
  if (!isK) {
    #pragma unroll
    for (int mi = 0; mi < 4; mi++)
      #pragma unroll
      for (int ni = 0; ni < 4; ni++) {
        int n = wrA * 64 + mi * 16 + r4;
        int tok = wcA * 64 + ni * 16 + l16;
        int head = (n >> 4) & 7;
        *(uint2*)(hLb + fra(head * 128 + tok, (n & 15) * 2)) = px[mi][ni];
      }
  }
  bar_lgkm();

  // ---- phase C: attention; wave = head; qf from LDS frag region; ao written
  // back into the consumed qf rows (per-head regions disjoint -> no races)
  {
    int dvt = wv * 16 + (l31 & 15);
    #pragma unroll 1
    for (int qt = 0; qt < 4; qt++) {
      bf16x8 qf = *(const bf16x8*)(hLb + fra(wv * 128 + 32 * qt + l31, hi * 16));
      f32x16 sc[4];
      __builtin_amdgcn_s_setprio(1);
      #pragma unroll
      for (int kt = 0; kt < 4; kt++) {
        f32x16 z = {};
        sc[kt] = __builtin_amdgcn_mfma_f32_32x32x16_bf16(kf[kt], qf, z, 0, 0, 0);
      }
      __builtin_amdgcn_s_setprio(0);
      // no-max softmax; 0.25*log2(e) pre-folded into Wq -> raw v_exp_f32.
      float sum = 0.f;
      uint4 pfw[8];
      #pragma unroll
      for (int s = 0; s < 8; s++) {
        int t = s >> 1, sl = (s & 1) * 8;
        float p0 = __builtin_amdgcn_exp2f(sc[t][sl + 0]);
        float p1 = __builtin_amdgcn_exp2f(sc[t][sl + 1]);
        float p2 = __builtin_amdgcn_exp2f(sc[t][sl + 2]);
        float p3 = __builtin_amdgcn_exp2f(sc[t][sl + 3]);
        float p4 = __builtin_amdgcn_exp2f(sc[t][sl + 4]);
        float p5 = __builtin_amdgcn_exp2f(sc[t][sl + 5]);
        float p6 = __builtin_amdgcn_exp2f(sc[t][sl + 6]);
        float p7 = __builtin_amdgcn_exp2f(sc[t][sl + 7]);
        sum += ((p0 + p1) + (p2 + p3)) + ((p4 + p5) + (p6 + p7));
        unsigned X0 = pkbf(p0, p1), X1 = pkbf(p2, p3);
        unsigned Y0 = pkbf(p4, p5), Y1 = pkbf(p6, p7);
        pl32swap(X0, Y0);
        pl32swap(X1, Y1);
        pfw[s] = (uint4){X0, X1, Y0, Y1};
      }
      sum += __shfl_xor(sum, 32);
      float inv = 1.0f / sum;
      // PV: two independent 4-deep MFMA chains (C0: s even, C1: s odd)
      f32x16 C0 = {}, C1 = {};
      __builtin_amdgcn_s_setprio(1);
      #pragma unroll
      for (int sp = 0; sp < 4; sp++) {
        int s0 = 2 * sp, s1 = 2 * sp + 1;
        bf16x8 pf0 = __builtin_bit_cast(bf16x8, pfw[s0]);
        bf16x8 vf0 = *(const bf16x8*)((const char*)vT +
                      ((dvt * 272 + (16 * s0 + 8 * hi) * 2) ^ VSW(dvt)));
        C0 = __builtin_amdgcn_mfma_f32_32x32x16_bf16(pf0, vf0, C0, 0, 0, 0);
        bf16x8 pf1 = __builtin_bit_cast(bf16x8, pfw[s1]);
        bf16x8 vf1 = *(const bf16x8*)((const char*)vT +
                      ((dvt * 272 + (16 * s1 + 8 * hi) * 2) ^ VSW(dvt)));
        C1 = __builtin_amdgcn_mfma_f32_32x32x16_bf16(pf1, vf1, C1, 0, 0, 0);
      }
      __builtin_amdgcn_s_setprio(0);
      #pragma unroll
      for (int e = 0; e < 16; e++) {
        int row = (e & 3) + 8 * (e >> 2) + 4 * hi;
        float rsv = __shfl(inv, row, 32);
        if (l31 < 16)
          *(bf16_t*)(hLb + fra(wv * 128 + 32 * qt + row, l31 * 2)) =
              (bf16_t)((C0[e] + C1[e]) * rsv);
      }
    }
  }
  bar_lgkm();

  // ---- phase D: out-projection + f32 residual; ao from frag layout
  {
    int wr = wv >> 2, wc = wv & 3;
    int qr = wr * 64, qc = wc * 32;
    f32x4 acc[4][2] = {};
    #pragma unroll
    for (int ks = 0; ks < 4; ks++) {
      int k0 = ks * 32 + gk;
      bf16x8 a[4], b[2];
      #pragma unroll
      for (int mi = 0; mi < 4; mi++)
        a[mi] = *(const bf16x8*)(hLb +
                 fra((k0 >> 4) * 128 + (qr + mi * 16 + l16), (k0 & 8) * 2));
      #pragma unroll
      for (int ni = 0; ni < 2; ni++)
        b[ni] = *(const bf16x8*)(Wot + (qc + ni * 16 + l16) * 128 + k0);
      #pragma unroll
      for (int mi = 0; mi < 4; mi++)
        #pragma unroll
        for (int ni = 0; ni < 2; ni++)
          acc[mi][ni] = __builtin_amdgcn_mfma_f32_16x16x32_bf16(a[mi], b[ni], acc[mi][ni], 0, 0, 0);
    }
    #pragma unroll
    for (int mi = 0; mi < 4; mi++) {
      #pragma unroll
      for (int e = 0; e < 4; e++) {
        int row = qr + mi * 16 + r4 + e;
        int tok = order[chunk * 128 + row];
        #pragma unroll
        for (int ni = 0; ni < 2; ni++) {
          int col = qc + ni * 16 + l16;
          xout[(size_t)tok * 128 + col] = xin[(size_t)tok * 128 + col] + acc[mi][ni][e];
        }
      }
    }
  }
}

extern "C" void kernel_launch(void* const* d_in, const int* in_sizes, int n_in,
                              void* d_out, int out_size, void* d_ws, size_t ws_size,
                              hipStream_t stream) {
  const int* coords = (const int*)d_in[0];
  const float* feats = (const float*)d_in[1];
  const float* Wqkv = (const float*)d_in[2];
  const float* Wo = (const float*)d_in[3];
  const float* ln_g = (const float*)d_in[4];
  const float* ln_b = (const float*)d_in[5];
  float* out = (float*)d_out;

  char* w = (char*)d_ws;
  size_t off = 0;
  auto take = [&](size_t b) { char* p = w + off; off += (b + 255) & ~(size_t)255; return p; };
  int* hist   = (int*)take(2 * HSTR * 4);
  int* starts = (int*)take(2 * HSTR * 4);
  int* cur    = (int*)take(2 * HSTR * 4);
  int* seg    = (int*)take(2 * (size_t)N_TOK * 4);
  int* order  = (int*)take(2 * (size_t)N_TOK * 4);
  bf16_t* Wt  = (bf16_t*)take(2 * 384 * 128 * 2);
  bf16_t* Wot = (bf16_t*)take(2 * 128 * 128 * 2);

  hipMemsetAsync(hist, 0, 2 * HSTR * 4, stream);
  k_pre<<<512, 256, 0, stream>>>(Wqkv, Wo, coords, Wt, Wot, hist);
  k_scan<<<2, 256, 0, stream>>>(hist, starts, cur);
  k_scatter<<<512, 256, 0, stream>>>(coords, cur, seg);
  k_winsort<<<dim3(NBINS, 2), 64, 0, stream>>>(starts, seg, order);

  for (int r = 0; r < 2; r++) {
    const float* xin = (r == 0) ? feats : out;
    k_fused<<<NCHUNK, 512, 0, stream>>>(Wt + r * 49152, Wot + r * 16384,
                                        order + r * N_TOK, ln_g + r * 128,
                                        ln_b + r * 128, xin, out);
  }
}

// Round 21
// 218.943 us; speedup vs baseline: 1.3950x; 1.0119x over previous
//
#include <hip/hip_runtime.h>
#include <hip/hip_bf16.h>

#define N_TOK 131072
#define NCHUNK 1024
#define NBINS 8192
#define HSTR 8448

typedef __bf16 bf16_t;
typedef bf16_t bf16x4 __attribute__((ext_vector_type(4)));
typedef bf16_t bf16x8 __attribute__((ext_vector_type(8)));
typedef float f32x4 __attribute__((ext_vector_type(4)));
typedef float f32x16 __attribute__((ext_vector_type(16)));

__device__ __forceinline__ unsigned pkbf(float a, float b) {
  unsigned r;
  asm("v_cvt_pk_bf16_f32 %0, %1, %2" : "=v"(r) : "v"(a), "v"(b));
  return r;
}
__device__ __forceinline__ void pl32swap(unsigned& x, unsigned& y) {
  asm("v_permlane32_swap_b32 %0, %1" : "+v"(x), "+v"(y));
}
// lgkm-only barrier: orders LDS traffic, leaves global loads/stores in flight.
// All inter-phase deps in k_fused are LDS-only (rule #18 sched_barrier incl.)
__device__ __forceinline__ void bar_lgkm() {
  asm volatile("s_waitcnt lgkmcnt(0)" ::: "memory");
  __builtin_amdgcn_s_barrier();
  __builtin_amdgcn_sched_barrier(0);
}
// fragment-region byte address inside the reused hL region:
// frow = head*128 + tok (0..1023), 32B per frag row, 272B super-rows.
__device__ __forceinline__ int fra(int frow, int colb) {
  return (frow >> 3) * 272 + (frow & 7) * 32 + colb;
}

// window key decomposition (matches reference _window_keys)
__device__ __forceinline__ void win_keys(int b, int z, int y, int x, int r,
                                         int& bwi, int& cell) {
  int wx = x / 12, wy = y / 12, wz = z >> 5;
  int cx = x % 12, cy = y % 12, cz = z & 31;
  if (r == 0) { bwi = b * 1922 + wx * 62 + wy * 2 + wz; cell = cx * 384 + cy * 32 + cz; }
  else        { bwi = b * 1922 + wy * 62 + wx * 2 + wz; cell = cy * 384 + cx * 32 + cz; }
}

// merged: weight prep + window histogram (independent work, one launch)
__global__ void k_pre(const float* __restrict__ Wqkv, const float* __restrict__ Wo,
                      const int* __restrict__ coords, bf16_t* __restrict__ Wt,
                      bf16_t* __restrict__ Wot, int* __restrict__ hist) {
  int t = blockIdx.x * 256 + threadIdx.x;
  if (t < 98304) {                    // 2 * 384 * 128, [i][n][k]
    int i = t / 49152, rem = t % 49152, n = rem / 128, k = rem % 128;
    float v = Wqkv[(i * 128 + k) * 384 + n];
    if (n < 128) v *= 0.36067376022224085f;   // fold 0.25*log2(e) into Wq
    Wt[t] = (bf16_t)v;
  } else {
    int u = t - 98304;                // 2 * 128 * 128, [i][e][d]
    int i = u / 16384, rem = u % 16384, e = rem / 128, d = rem % 128;
    Wot[u] = (bf16_t)Wo[(i * 128 + d) * 128 + e];
  }
  int4 c = ((const int4*)coords)[t];  // b,z,y,x
  int bwi, cell;
  win_keys(c.x, c.y, c.z, c.w, 0, bwi, cell);
  atomicAdd(&hist[bwi], 1);
  win_keys(c.x, c.y, c.z, c.w, 1, bwi, cell);
  atomicAdd(&hist[HSTR + bwi], 1);
}

// block-parallel exclusive scan (Hillis-Steele over 256 partials)
__global__ void k_scan(const int* __restrict__ histb, int* __restrict__ startsb,
                       int* __restrict__ curb) {
  int r = blockIdx.x;
  const int* hist = histb + r * HSTR;
  int* starts = startsb + r * HSTR;
  int* cur = curb + r * HSTR;
  __shared__ int ssum[256];
  int tid = threadIdx.x;
  int base = tid * 32;
  int s = 0;
  for (int j = 0; j < 32; j++) s += hist[base + j];
  ssum[tid] = s;
  __syncthreads();
  int val = s;
  #pragma unroll
  for (int off = 1; off < 256; off <<= 1) {
    int t = (tid >= off) ? ssum[tid - off] : 0;
    __syncthreads();
    val += t;
    ssum[tid] = val;
    __syncthreads();
  }
  int run = val - s;   // exclusive prefix
  for (int j = 0; j < 32; j++) {
    starts[base + j] = run; cur[base + j] = run; run += hist[base + j];
  }
  if (tid == 255) starts[NBINS] = run;
}

__global__ void k_scatter(const int* __restrict__ coords, int* __restrict__ cur,
                          int* __restrict__ seg) {
  int t = blockIdx.x * 256 + threadIdx.x;
  int4 c = ((const int4*)coords)[t];
  int bwi, cell;
  win_keys(c.x, c.y, c.z, c.w, 0, bwi, cell);
  seg[atomicAdd(&cur[bwi], 1)] = (cell << 17) | t;
  win_keys(c.x, c.y, c.z, c.w, 1, bwi, cell);
  seg[N_TOK + atomicAdd(&cur[HSTR + bwi], 1)] = (cell << 17) | t;
}

// per-window stable finish: sort segment ascending by packed (cell, idx).
// Window staged in LDS once (m<=128 always in practice; global fallback kept).
__global__ void k_winsort(const int* __restrict__ startsb, const int* __restrict__ segb,
                          int* __restrict__ orderb) {
  int r = blockIdx.y;
  const int* starts = startsb + r * HSTR;
  const int* seg = segb + r * N_TOK;
  int* order = orderb + r * N_TOK;
  int w = blockIdx.x;
  int s = starts[w], m = starts[w + 1] - s;
  if (m <= 0) return;
  __shared__ int sw[128];
  if (m <= 128) {
    for (int i = threadIdx.x; i < m; i += 64) sw[i] = seg[s + i];
    __syncthreads();
    for (int i = threadIdx.x; i < m; i += 64) {
      int v = sw[i], rk = 0;
      for (int j = 0; j < m; j++) rk += (sw[j] < v);
      order[s + rk] = v & 0x1FFFF;
    }
  } else {
    for (int i = threadIdx.x; i < m; i += 64) {
      int v = seg[s + i], rk = 0;
      for (int j = 0; j < m; j++) rk += (seg[s + j] < v);
      order[s + rk] = v & 0x1FFFF;
    }
  }
}

// ======================== fused per-chunk block (v4 + lgkm + split-C) ========
// 512 thr / 8 waves. LDS: hL[128][136] + vT[128][136] = 69.6 KB -> 2 blocks/CU.
// Q/K handoff entirely in LDS (hL region reused as fragment buffer). lgkm-only
// barriers. PV accumulator split C0/C1 to halve the dependent-MFMA chain.
#define VSW(d) ((((d) >> 3) & 7) << 4)
__global__ __launch_bounds__(512, 4) void k_fused(
    const bf16_t* __restrict__ Wt, const bf16_t* __restrict__ Wot,
    const int* __restrict__ order, const float* __restrict__ ln_g,
    const float* __restrict__ ln_b, const float* __restrict__ xin,
    float* __restrict__ xout) {
  int chunk = blockIdx.x;
  __shared__ bf16_t hL[128 * 136];
  __shared__ bf16_t vT[128 * 136];
  char* hLb = (char*)hL;
  int tid = threadIdx.x, wv = tid >> 6, lane = tid & 63;
  int l16 = lane & 15, gk = 8 * (lane >> 4), r4 = (lane >> 4) * 4;
  int l31 = lane & 31, hi = lane >> 5;

  // ---- phase 0: gather + layernorm -> hL (4 threads per row)
  {
    int row = tid >> 2, g = tid & 3;
    int tok = order[chunk * 128 + row];
    const float4* src = (const float4*)(xin + (size_t)tok * 128) + g * 8;
    float4 v[8];
    #pragma unroll
    for (int j = 0; j < 8; j++) v[j] = src[j];
    float s = 0.f, sq = 0.f;
    #pragma unroll
    for (int j = 0; j < 8; j++) {
      s += v[j].x + v[j].y + v[j].z + v[j].w;
      sq += v[j].x * v[j].x + v[j].y * v[j].y + v[j].z * v[j].z + v[j].w * v[j].w;
    }
    s += __shfl_xor(s, 1); sq += __shfl_xor(sq, 1);
    s += __shfl_xor(s, 2); sq += __shfl_xor(sq, 2);
    float mean = s * 0.0078125f;
    float var = sq * 0.0078125f - mean * mean;
    float rstd = rsqrtf(var + 1e-5f);
    #pragma unroll
    for (int j = 0; j < 8; j++) {
      float4 gv = ((const float4*)ln_g)[g * 8 + j];
      float4 bv = ((const float4*)ln_b)[g * 8 + j];
      bf16x4 o;
      o[0] = (bf16_t)((v[j].x - mean) * rstd * gv.x + bv.x);
      o[1] = (bf16_t)((v[j].y - mean) * rstd * gv.y + bv.y);
      o[2] = (bf16_t)((v[j].z - mean) * rstd * gv.z + bv.z);
      o[3] = (bf16_t)((v[j].w - mean) * rstd * gv.w + bv.w);
      *(bf16x4*)(&hL[row * 136 + g * 32 + j * 4]) = o;
    }
  }
  bar_lgkm();

  // ---- phase B: V projection: C[tok][d] -> swizzled vT[d][tok] (LDS)
  {
    int wr = wv >> 2, wc = wv & 3;       // 64-tok block, 32-d block
    f32x4 acc[4][2] = {};
    #pragma unroll
    for (int ks = 0; ks < 4; ks++) {
      int k0 = ks * 32 + gk;
      bf16x8 a[4], b[2];
      #pragma unroll
      for (int mi = 0; mi < 4; mi++)
        a[mi] = *(const bf16x8*)(&hL[(wr * 64 + mi * 16 + l16) * 136 + k0]);
      #pragma unroll
      for (int ni = 0; ni < 2; ni++)
        b[ni] = *(const bf16x8*)(Wt + (size_t)(256 + wc * 32 + ni * 16 + l16) * 128 + k0);
      #pragma unroll
      for (int mi = 0; mi < 4; mi++)
        #pragma unroll
        for (int ni = 0; ni < 2; ni++)
          acc[mi][ni] = __builtin_amdgcn_mfma_f32_16x16x32_bf16(a[mi], b[ni], acc[mi][ni], 0, 0, 0);
    }
    #pragma unroll
    for (int mi = 0; mi < 4; mi++)
      #pragma unroll
      for (int ni = 0; ni < 2; ni++) {
        int d = wc * 32 + ni * 16 + l16;
        int tok0 = wr * 64 + mi * 16 + r4;
        bf16x4 o;
        #pragma unroll
        for (int e = 0; e < 4; e++) o[e] = (bf16_t)acc[mi][ni][e];
        *(bf16x4*)((char*)vT + ((d * 272 + tok0 * 2) ^ VSW(d))) = o;
      }
  }

  // ---- phase A: QK projection (swapped: C[n][tok]); pieces held in regs
  uint2 px[4][4];
  int wrA = wv >> 1, wcA = wv & 1;       // 64-n block, 64-tok block
  {
    f32x4 acc[4][4] = {};
    #pragma unroll
    for (int ks = 0; ks < 4; ks++) {
      int k0 = ks * 32 + gk;
      bf16x8 a[4], b[4];
      #pragma unroll
      for (int mi = 0; mi < 4; mi++)
        a[mi] = *(const bf16x8*)(Wt + (size_t)(wrA * 64 + mi * 16 + l16) * 128 + k0);
      #pragma unroll
      for (int ni = 0; ni < 4; ni++)
        b[ni] = *(const bf16x8*)(&hL[(wcA * 64 + ni * 16 + l16) * 136 + k0]);
      #pragma unroll
      for (int mi = 0; mi < 4; mi++)
        #pragma unroll
        for (int ni = 0; ni < 4; ni++)
          acc[mi][ni] = __builtin_amdgcn_mfma_f32_16x16x32_bf16(a[mi], b[ni], acc[mi][ni], 0, 0, 0);
    }
    #pragma unroll
    for (int mi = 0; mi < 4; mi++)
      #pragma unroll
      for (int ni = 0; ni < 4; ni++) {
        bf16x4 o;
        #pragma unroll
        for (int e = 0; e < 4; e++) o[e] = (bf16_t)acc[mi][ni][e];
        px[mi][ni] = __builtin_bit_cast(uint2, o);
      }
  }
  bar_lgkm();   // all hL(h) + vT deps done; hL region now reusable

  // ---- K-frag write (waves with n>=128), then kf load, then Q-frag write
  bool isK = (wv >= 4);
  if (isK) {
    #pragma unroll
    for (int mi = 0; mi < 4; mi++)
      #pragma unroll
      for (int ni = 0; ni < 4; ni++) {
        int n = wrA * 64 + mi * 16 + r4;
        int tok = wcA * 64 + ni * 16 + l16;
        int head = (n >> 4) & 7;
        *(uint2*)(hLb + fra(head * 128 + tok, (n & 15) * 2)) = px[mi][ni];
      }
  }
  bar_lgkm();
  bf16x8 kf[4];
  #pragma unroll
  for (int kt = 0; kt < 4; kt++)
    kf[kt] = *(const bf16x8*)(hLb + fra(wv * 128 + 32 * kt + l31, hi * 16));
  bar_lgkm();
  if (!isK) {
    #pragma unroll
    for (int mi = 0; mi < 4; mi++)
      #pragma unroll
      for (int ni = 0; ni < 4; ni++) {
        int n = wrA * 64 + mi * 16 + r4;
        int tok = wcA * 64 + ni * 16 + l16;
        int head = (n >> 4) & 7;
        *(uint2*)(hLb + fra(head * 128 + tok, (n & 15) * 2)) = px[mi][ni];
      }
  }
  bar_lgkm();

  // ---- phase C: attention; wave = head; qf from LDS frag region; ao written
  // back into the consumed qf rows (per-head regions disjoint -> no races)
  {
    int dvt = wv * 16 + (l31 & 15);
    #pragma unroll 1
    for (int qt = 0; qt < 4; qt++) {
      bf16x8 qf = *(const bf16x8*)(hLb + fra(wv * 128 + 32 * qt + l31, hi * 16));
      f32x16 sc[4];
      __builtin_amdgcn_s_setprio(1);
      #pragma unroll
      for (int kt = 0; kt < 4; kt++) {
        f32x16 z = {};
        sc[kt] = __builtin_amdgcn_mfma_f32_32x32x16_bf16(kf[kt], qf, z, 0, 0, 0);
      }
      __builtin_amdgcn_s_setprio(0);
      // no-max softmax; 0.25*log2(e) pre-folded into Wq -> raw v_exp_f32.
      float sum = 0.f;
      uint4 pfw[8];
      #pragma unroll
      for (int s = 0; s < 8; s++) {
        int t = s >> 1, sl = (s & 1) * 8;
        float p0 = __builtin_amdgcn_exp2f(sc[t][sl + 0]);
        float p1 = __builtin_amdgcn_exp2f(sc[t][sl + 1]);
        float p2 = __builtin_amdgcn_exp2f(sc[t][sl + 2]);
        float p3 = __builtin_amdgcn_exp2f(sc[t][sl + 3]);
        float p4 = __builtin_amdgcn_exp2f(sc[t][sl + 4]);
        float p5 = __builtin_amdgcn_exp2f(sc[t][sl + 5]);
        float p6 = __builtin_amdgcn_exp2f(sc[t][sl + 6]);
        float p7 = __builtin_amdgcn_exp2f(sc[t][sl + 7]);
        sum += ((p0 + p1) + (p2 + p3)) + ((p4 + p5) + (p6 + p7));
        unsigned X0 = pkbf(p0, p1), X1 = pkbf(p2, p3);
        unsigned Y0 = pkbf(p4, p5), Y1 = pkbf(p6, p7);
        pl32swap(X0, Y0);
        pl32swap(X1, Y1);
        pfw[s] = (uint4){X0, X1, Y0, Y1};
      }
      sum += __shfl_xor(sum, 32);
      float inv = 1.0f / sum;
      // PV: two independent 4-deep MFMA chains (C0: s even, C1: s odd)
      f32x16 C0 = {}, C1 = {};
      __builtin_amdgcn_s_setprio(1);
      #pragma unroll
      for (int sp = 0; sp < 4; sp++) {
        int s0 = 2 * sp, s1 = 2 * sp + 1;
        bf16x8 pf0 = __builtin_bit_cast(bf16x8, pfw[s0]);
        bf16x8 vf0 = *(const bf16x8*)((const char*)vT +
                      ((dvt * 272 + (16 * s0 + 8 * hi) * 2) ^ VSW(dvt)));
        C0 = __builtin_amdgcn_mfma_f32_32x32x16_bf16(pf0, vf0, C0, 0, 0, 0);
        bf16x8 pf1 = __builtin_bit_cast(bf16x8, pfw[s1]);
        bf16x8 vf1 = *(const bf16x8*)((const char*)vT +
                      ((dvt * 272 + (16 * s1 + 8 * hi) * 2) ^ VSW(dvt)));
        C1 = __builtin_amdgcn_mfma_f32_32x32x16_bf16(pf1, vf1, C1, 0, 0, 0);
      }
      __builtin_amdgcn_s_setprio(0);
      #pragma unroll
      for (int e = 0; e < 16; e++) {
        int row = (e & 3) + 8 * (e >> 2) + 4 * hi;
        float rsv = __shfl(inv, row, 32);
        if (l31 < 16)
          *(bf16_t*)(hLb + fra(wv * 128 + 32 * qt + row, l31 * 2)) =
              (bf16_t)((C0[e] + C1[e]) * rsv);
      }
    }
  }
  bar_lgkm();

  // ---- phase D: out-projection + f32 residual; ao from frag layout
  {
    int wr = wv >> 2, wc = wv & 3;
    int qr = wr * 64, qc = wc * 32;
    f32x4 acc[4][2] = {};
    #pragma unroll
    for (int ks = 0; ks < 4; ks++) {
      int k0 = ks * 32 + gk;
      bf16x8 a[4], b[2];
      #pragma unroll
      for (int mi = 0; mi < 4; mi++)
        a[mi] = *(const bf16x8*)(hLb +
                 fra((k0 >> 4) * 128 + (qr + mi * 16 + l16), (k0 & 8) * 2));
      #pragma unroll
      for (int ni = 0; ni < 2; ni++)
        b[ni] = *(const bf16x8*)(Wot + (qc + ni * 16 + l16) * 128 + k0);
      #pragma unroll
      for (int mi = 0; mi < 4; mi++)
        #pragma unroll
        for (int ni = 0; ni < 2; ni++)
          acc[mi][ni] = __builtin_amdgcn_mfma_f32_16x16x32_bf16(a[mi], b[ni], acc[mi][ni], 0, 0, 0);
    }
    #pragma unroll
    for (int mi = 0; mi < 4; mi++) {
      #pragma unroll
      for (int e = 0; e < 4; e++) {
        int row = qr + mi * 16 + r4 + e;
        int tok = order[chunk * 128 + row];
        #pragma unroll
        for (int ni = 0; ni < 2; ni++) {
          int col = qc + ni * 16 + l16;
          xout[(size_t)tok * 128 + col] = xin[(size_t)tok * 128 + col] + acc[mi][ni][e];
        }
      }
    }
  }
}

extern "C" void kernel_launch(void* const* d_in, const int* in_sizes, int n_in,
                              void* d_out, int out_size, void* d_ws, size_t ws_size,
                              hipStream_t stream) {
  const int* coords = (const int*)d_in[0];
  const float* feats = (const float*)d_in[1];
  const float* Wqkv = (const float*)d_in[2];
  const float* Wo = (const float*)d_in[3];
  const float* ln_g = (const float*)d_in[4];
  const float* ln_b = (const float*)d_in[5];
  float* out = (float*)d_out;

  char* w = (char*)d_ws;
  size_t off = 0;
  auto take = [&](size_t b) { char* p = w + off; off += (b + 255) & ~(size_t)255; return p; };
  int* hist   = (int*)take(2 * HSTR * 4);
  int* starts = (int*)take(2 * HSTR * 4);
  int* cur    = (int*)take(2 * HSTR * 4);
  int* seg    = (int*)take(2 * (size_t)N_TOK * 4);
  int* order  = (int*)take(2 * (size_t)N_TOK * 4);
  bf16_t* Wt  = (bf16_t*)take(2 * 384 * 128 * 2);
  bf16_t* Wot = (bf16_t*)take(2 * 128 * 128 * 2);

  hipMemsetAsync(hist, 0, 2 * HSTR * 4, stream);
  k_pre<<<512, 256, 0, stream>>>(Wqkv, Wo, coords, Wt, Wot, hist);
  k_scan<<<2, 256, 0, stream>>>(hist, starts, cur);
  k_scatter<<<512, 256, 0, stream>>>(coords, cur, seg);
  k_winsort<<<dim3(NBINS, 2), 64, 0, stream>>>(starts, seg, order);

  for (int r = 0; r < 2; r++) {
    const float* xin = (r == 0) ? feats : out;
    k_fused<<<NCHUNK, 512, 0, stream>>>(Wt + r * 49152, Wot + r * 16384,
                                        order + r * N_TOK, ln_g + r * 128,
                                        ln_b + r * 128, xin, out);
  }
}